// Round 10
// baseline (114.110 us; speedup 1.0000x reference)
//
#include <hip/hip_runtime.h>
#include <hip/hip_bf16.h>

#define CC 64
#define HH 128
#define WW 128
#define OO 576   // C * K * K
#define HW (HH * WW)

typedef __attribute__((ext_vector_type(8))) short short8;
typedef __attribute__((ext_vector_type(4))) float floatx4;

__device__ __forceinline__ unsigned short f2bf(float f) {
    unsigned u = __float_as_uint(f);
    u = (u + 0x7FFFu + ((u >> 16) & 1u)) >> 16;   // RTNE
    return (unsigned short)u;
}

// Pre-pass: (1) W_gen (576x64 fp32) -> bf16, PERMUTED tap-major (row o' =
// kk*64 + c  <-  src row o = c*9 + kk); (2) bias permuted tap-major f32:
// Bp[kk*64 + c] = bg[c*9 + kk]  (main kernel then loads bias as ONE b128).
__global__ void ACDA_wconv_kernel(const float* __restrict__ Wg,
                                  const float* __restrict__ bg,
                                  unsigned short* __restrict__ Wb,
                                  float* __restrict__ Bp) {
    int i = blockIdx.x * 256 + threadIdx.x;
    if (i < OO * CC) {
        int o2  = i >> 6;          // dest row
        int col = i & 63;
        int kk  = o2 >> 6;         // 0..8
        int c   = o2 & 63;
        Wb[i] = f2bf(Wg[(c * 9 + kk) * CC + col]);
    }
    if (i < OO) {                  // 576 permuted biases
        Bp[i] = bg[(i & 63) * 9 + (i >> 6)];
    }
}

// R9 post-mortem: VGPR=68 -> allocator could not hoist the 9 taps' A/bias
// (needs 108 regs), so each tap serialized on 2-3 dependent L2 loads -- the
// same allocator-dissolved-pipeline failure as R4/5/7, now on the A side.
// Occupancy is LDS-capped at 3 blocks/CU (= 3 waves/SIMD) regardless, so
// launch_bounds(256,3) (VGPR cap ~170) costs nothing and buys the hoist:
// ALL A-fragments + biases loaded into regs BEFORE the barrier (latency
// lands under staging drain + barrier + bfrag pack). Tap loop is now pure
// ds_read_b128 + MFMA + FMA: zero global loads.
__global__ __launch_bounds__(256, 3) void ACDA_main_kernel(
    const float* __restrict__ x, const unsigned short* __restrict__ Wb,
    const float* __restrict__ Bp, float* __restrict__ out)
{
    // S[di][s][c]: di = tap row (h-1,h,h+1; zeroed if OOB), s = col slot
    // (0 = left halo, 1..64 = w0..w0+63, 65 = right halo; halos zeroed at
    // image edge), c = channel (padded to 68 for b128 alignment).
    __shared__ float S[3][66][68];   // 53856 B -> 3 blocks/CU
    float* Sf = &S[0][0][0];

    const int tid  = threadIdx.x;
    const int lane = tid & 63;
    const int wv   = tid >> 6;       // 16-channel group (wave-uniform)
    const int quad = lane >> 4;
    const int l16  = lane & 15;
    const int c0   = wv * 16;

    // Bijective XCD swizzle (proven: FETCH 85->17 MB).
    const int bid = blockIdx.x;
    const int wk  = (bid & 7) * 256 + (bid >> 3);
    const int seg = wk & 1;
    const int h   = (wk >> 1) & 127;
    const int b   = wk >> 8;
    const int w0  = seg << 6;

    const float* xb = x + (size_t)b * CC * HW;

    // ---- cooperative slab staging (channel-inner, zero-filled OOB) ----
#pragma unroll
    for (int di = 0; di < 3; ++di) {
        const int hh = h + di - 1;
        const bool oob = (hh < 0) || (hh > 127);     // block-uniform branch
        const int hc = hh < 0 ? 0 : (hh > 127 ? 127 : hh);
        const float* src = xb + hc * WW + w0 + lane;
#pragma unroll
        for (int i2 = 0; i2 < 4; ++i2) {
            const int c = c0 + 4 * i2;
            floatx4 v;
            if (!oob) {
                v[0] = src[(c + 0) * HW]; v[1] = src[(c + 1) * HW];
                v[2] = src[(c + 2) * HW]; v[3] = src[(c + 3) * HW];
            } else {
                v = floatx4{0.f, 0.f, 0.f, 0.f};
            }
            *(floatx4*)&Sf[(di * 66 + lane + 1) * 68 + c] = v;
        }
    }
    if (tid < 192) {   // halo cols (zero at image edge)
        const int di = tid >> 6, c = tid & 63;
        const int hh = h + di - 1;
        const bool oobR = (hh < 0) || (hh > 127);
        const int hc = hh < 0 ? 0 : (hh > 127 ? 127 : hh);
        float vL = 0.f, vR = 0.f;
        if (!oobR) {
            if (w0 > 0)        vL = xb[c * HW + hc * WW + w0 - 1];
            if (w0 + 64 < WW)  vR = xb[c * HW + hc * WW + w0 + 64];
        }
        Sf[(di * 66 + 0)  * 68 + c] = vL;
        Sf[(di * 66 + 65) * 68 + c] = vR;
    }

    // ---- HOIST: all 9 taps' A-fragments + biases into registers NOW ----
    // 27 independent b128 loads (L2-hot: only 4 distinct sets grid-wide).
    // Issued before the barrier: latency hides under staging drain +
    // barrier + bfrag pack. Compile-time indices only (full unroll).
    short8  a0v[9], a1v[9];
    floatx4 bvv[9];
#pragma unroll
    for (int t = 0; t < 9; ++t) {
        const unsigned short* wrow = Wb + (t * 64 + c0 + l16) * CC + quad * 8;
        a0v[t] = *(const short8*)(wrow);
        a1v[t] = *(const short8*)(wrow + 32);
        bvv[t] = *(const floatx4*)(Bp + t * 64 + c0 + 4 * quad);
    }

    __syncthreads();   // the ONLY barrier; S read-only afterwards

    // ---- B fragments from slab row di=1: two b128 per (nt,ks), pack ----
    short8 bfrag[4][2];
#pragma unroll
    for (int nt = 0; nt < 4; ++nt)
#pragma unroll
        for (int ks = 0; ks < 2; ++ks) {
            const float* p = &Sf[(66 + nt * 16 + l16 + 1) * 68 + ks * 32 + quad * 8];
            floatx4 f0 = *(const floatx4*)p;
            floatx4 f1 = *(const floatx4*)(p + 4);
            short8 v;
            __hip_bfloat162 p0 = __float22bfloat162_rn(make_float2(f0[0], f0[1]));
            __hip_bfloat162 p1 = __float22bfloat162_rn(make_float2(f0[2], f0[3]));
            __hip_bfloat162 p2 = __float22bfloat162_rn(make_float2(f1[0], f1[1]));
            __hip_bfloat162 p3 = __float22bfloat162_rn(make_float2(f1[2], f1[3]));
            unsigned u0, u1, u2, u3;
            __builtin_memcpy(&u0, &p0, 4); __builtin_memcpy(&u1, &p1, 4);
            __builtin_memcpy(&u2, &p2, 4); __builtin_memcpy(&u3, &p3, 4);
            v[0] = (short)(u0 & 0xffffu); v[1] = (short)(u0 >> 16);
            v[2] = (short)(u1 & 0xffffu); v[3] = (short)(u1 >> 16);
            v[4] = (short)(u2 & 0xffffu); v[5] = (short)(u2 >> 16);
            v[6] = (short)(u3 & 0xffffu); v[7] = (short)(u3 >> 16);
            bfrag[nt][ks] = v;
        }

    // Output accumulator in MFMA layout: acc[nt][rg] <-> channel
    // c0+4*quad+rg, pixel w0+16*nt+l16.
    floatx4 acc[4];
#pragma unroll
    for (int nt = 0; nt < 4; ++nt) acc[nt] = floatx4{0.f, 0.f, 0.f, 0.f};

    // ---- 9 taps, fully unrolled, ZERO global loads: per tap 4x
    // ds_read_b128 + 8 MFMA (bias as acc-init) + 16 relu-FMA.
#pragma unroll
    for (int t = 0; t < 9; ++t) {
        const int di = t / 3;
        const int dj = t - 3 * di;
#pragma unroll
        for (int nt = 0; nt < 4; ++nt) {
            floatx4 pv = *(const floatx4*)&Sf[(di * 66 + nt * 16 + l16 + dj) * 68 + c0 + 4 * quad];
            floatx4 z = bvv[t];   // bias pre-ReLU as accumulator init
            z = __builtin_amdgcn_mfma_f32_16x16x32_bf16(a0v[t], bfrag[nt][0], z, 0, 0, 0);
            z = __builtin_amdgcn_mfma_f32_16x16x32_bf16(a1v[t], bfrag[nt][1], z, 0, 0, 0);
#pragma unroll
            for (int rg = 0; rg < 4; ++rg)
                acc[nt][rg] = fmaf(fmaxf(z[rg], 0.f), pv[rg], acc[nt][rg]);
        }
    }

    // ---- epilogue: stores directly from MFMA-layout acc ----
    float* ob = out + (size_t)b * CC * HW + h * WW + w0;
#pragma unroll
    for (int nt = 0; nt < 4; ++nt)
#pragma unroll
        for (int rg = 0; rg < 4; ++rg)
            ob[(c0 + 4 * quad + rg) * HW + nt * 16 + l16] = acc[nt][rg];
}

extern "C" void kernel_launch(void* const* d_in, const int* in_sizes, int n_in,
                              void* d_out, int out_size, void* d_ws, size_t ws_size,
                              hipStream_t stream) {
    const float* x  = (const float*)d_in[0];
    const float* Wg = (const float*)d_in[1];
    const float* bg = (const float*)d_in[2];
    float* out = (float*)d_out;
    unsigned short* Wb = (unsigned short*)d_ws;            // 73728 B
    float* Bp = (float*)((char*)d_ws + OO * CC * 2);       // + 2304 B = 76032 B total

    ACDA_wconv_kernel<<<dim3((OO * CC + 255) / 256), dim3(256), 0, stream>>>(Wg, bg, Wb, Bp);
    ACDA_main_kernel<<<dim3(8 * 128 * 2), dim3(256), 0, stream>>>(x, Wb, Bp, out);
}

// Round 11
// 110.550 us; speedup vs baseline: 1.0322x; 1.0322x over previous
//
#include <hip/hip_runtime.h>
#include <hip/hip_bf16.h>

#define CC 64
#define HH 128
#define WW 128
#define OO 576   // C * K * K
#define HW (HH * WW)

typedef __attribute__((ext_vector_type(8))) short short8;
typedef __attribute__((ext_vector_type(4))) short short4v;
typedef __attribute__((ext_vector_type(4))) float floatx4;

__device__ __forceinline__ unsigned short f2bf(float f) {
    unsigned u = __float_as_uint(f);
    u = (u + 0x7FFFu + ((u >> 16) & 1u)) >> 16;   // RTNE
    return (unsigned short)u;
}

__device__ __forceinline__ float bf2f(short s) {
    return __uint_as_float(((unsigned)(unsigned short)s) << 16);
}

__device__ __forceinline__ short8 pack8(floatx4 a, floatx4 b) {
    __hip_bfloat162 p0 = __float22bfloat162_rn(make_float2(a[0], a[1]));
    __hip_bfloat162 p1 = __float22bfloat162_rn(make_float2(a[2], a[3]));
    __hip_bfloat162 p2 = __float22bfloat162_rn(make_float2(b[0], b[1]));
    __hip_bfloat162 p3 = __float22bfloat162_rn(make_float2(b[2], b[3]));
    unsigned u0, u1, u2, u3;
    __builtin_memcpy(&u0, &p0, 4); __builtin_memcpy(&u1, &p1, 4);
    __builtin_memcpy(&u2, &p2, 4); __builtin_memcpy(&u3, &p3, 4);
    short8 v;
    v[0] = (short)(u0 & 0xffffu); v[1] = (short)(u0 >> 16);
    v[2] = (short)(u1 & 0xffffu); v[3] = (short)(u1 >> 16);
    v[4] = (short)(u2 & 0xffffu); v[5] = (short)(u2 >> 16);
    v[6] = (short)(u3 & 0xffffu); v[7] = (short)(u3 >> 16);
    return v;
}

// Pre-pass: (1) W_gen -> bf16, tap-major (row o' = kk*64 + c); (2) bias
// permuted tap-major f32: Bp[kk*64 + c] = bg[c*9 + kk].
__global__ void ACDA_wconv_kernel(const float* __restrict__ Wg,
                                  const float* __restrict__ bg,
                                  unsigned short* __restrict__ Wb,
                                  float* __restrict__ Bp) {
    int i = blockIdx.x * 256 + threadIdx.x;
    if (i < OO * CC) {
        int o2  = i >> 6;
        int col = i & 63;
        int kk  = o2 >> 6;
        int c   = o2 & 63;
        Wb[i] = f2bf(Wg[(c * 9 + kk) * CC + col]);
    }
    if (i < OO) Bp[i] = bg[(i & 63) * 9 + (i >> 6)];
}

// R10 post-mortem: allocator dissolved the A-hoist again (VGPR 84, flat).
// Root arithmetic: time = generations x block-lifetime; generations =
// 2048/(256 x resident). The 54KB f32 slab caps residency at 3 blocks/CU
// -> 2.67 generations of ~16us latency-stalled lifetime = 43us, immune to
// schedule changes. THE LEVER IS RESIDENCY: bf16 slab = 28.5KB -> 5
// blocks/CU -> 1.6 generations. Side wins: bfrag pack deleted (direct
// short8 ds_read; B was already bf16-rounded), all LDS phases at the
// structural bank minimum (stride 144B = 4 banks). Patches are now bf16
// (one extra RTNE per product; predicted absmax ~0.15, tripwire 0.2).
__global__ __launch_bounds__(256, 5) void ACDA_main_kernel(
    const float* __restrict__ x, const unsigned short* __restrict__ Wb,
    const float* __restrict__ Bp, float* __restrict__ out)
{
    // S[di][s][c]: di = tap row (zeroed if OOB), s = col slot (0 = left
    // halo, 1..64 = w0..w0+63, 65 = right halo; zeroed at image edge),
    // c = channel, padded 64->72 (row stride 144B: 16B-aligned for b128,
    // bank stride 4 -> every b128/b64 phase at structural minimum).
    __shared__ short S[3][66][72];   // 28512 B -> 5 blocks/CU

    const int tid  = threadIdx.x;
    const int lane = tid & 63;
    const int wv   = tid >> 6;       // 16-channel group (wave-uniform)
    const int quad = lane >> 4;
    const int l16  = lane & 15;
    const int c0   = wv * 16;

    // Bijective XCD swizzle (proven: FETCH 85->17 MB).
    const int bid = blockIdx.x;
    const int wk  = (bid & 7) * 256 + (bid >> 3);
    const int seg = wk & 1;
    const int h   = (wk >> 1) & 127;
    const int b   = wk >> 8;
    const int w0  = seg << 6;

    const float* xb = x + (size_t)b * CC * HW;

    // ---- cooperative slab staging (bf16, zero-filled OOB) ----
    // Thread (wv,lane): col w0+lane -> slot lane+1, channels c0..c0+15.
    // Global: coalesced row-streams; LDS: 2x ds_write_b128 per di.
#pragma unroll
    for (int di = 0; di < 3; ++di) {
        const int hh = h + di - 1;
        const bool oob = (hh < 0) || (hh > 127);     // block-uniform
        const int hc = hh < 0 ? 0 : (hh > 127 ? 127 : hh);
        const float* src = xb + hc * WW + w0 + lane;
#pragma unroll
        for (int hf = 0; hf < 2; ++hf) {
            const int c = c0 + 8 * hf;
            short8 v8;
            if (!oob) {
                floatx4 va, vb;
                va[0] = src[(c + 0) * HW]; va[1] = src[(c + 1) * HW];
                va[2] = src[(c + 2) * HW]; va[3] = src[(c + 3) * HW];
                vb[0] = src[(c + 4) * HW]; vb[1] = src[(c + 5) * HW];
                vb[2] = src[(c + 6) * HW]; vb[3] = src[(c + 7) * HW];
                v8 = pack8(va, vb);
            } else {
                v8 = short8{0, 0, 0, 0, 0, 0, 0, 0};
            }
            *(short8*)&S[di][lane + 1][c] = v8;
        }
    }
    if (tid < 192) {   // halo cols (zero at image edge)
        const int di = tid >> 6, c = tid & 63;
        const int hh = h + di - 1;
        const bool oob = (hh < 0) || (hh > 127);
        const int hc = hh < 0 ? 0 : (hh > 127 ? 127 : hh);
        unsigned short vL = 0, vR = 0;
        if (!oob) {
            if (w0 > 0)       vL = f2bf(xb[c * HW + hc * WW + w0 - 1]);
            if (w0 + 64 < WW) vR = f2bf(xb[c * HW + hc * WW + w0 + 64]);
        }
        S[di][0][c]  = (short)vL;
        S[di][65][c] = (short)vR;
    }
    __syncthreads();   // the ONLY barrier; S read-only afterwards

    // ---- B fragments: DIRECT short8 ds_read (no packing; x row h) ----
    short8 bfrag[4][2];
#pragma unroll
    for (int nt = 0; nt < 4; ++nt)
#pragma unroll
        for (int ks = 0; ks < 2; ++ks)
            bfrag[nt][ks] = *(const short8*)&S[1][nt * 16 + l16 + 1][ks * 32 + quad * 8];

    // Output accumulator in MFMA layout: acc[nt][rg] <-> channel
    // c0+4*quad+rg, pixel w0+16*nt+l16.
    floatx4 acc[4];
#pragma unroll
    for (int nt = 0; nt < 4; ++nt) acc[nt] = floatx4{0.f, 0.f, 0.f, 0.f};

    // ---- 9 taps, fully unrolled. Per tap: A 2xb128 + bias b128 (global,
    // L2/L1-hot, in-loop -- R8 style beat both hoist attempts); 4x
    // ds_read_b64 patches; 8 MFMA (bias as acc-init); 16 relu-FMA.
#pragma unroll
    for (int t = 0; t < 9; ++t) {
        const int di = t / 3;
        const int dj = t - 3 * di;
        const unsigned short* wrow = Wb + (t * 64 + c0 + l16) * CC + quad * 8;
        short8 a0 = *(const short8*)(wrow);
        short8 a1 = *(const short8*)(wrow + 32);
        floatx4 bv = *(const floatx4*)(Bp + t * 64 + c0 + 4 * quad);
#pragma unroll
        for (int nt = 0; nt < 4; ++nt) {
            short4v ph = *(const short4v*)&S[di][nt * 16 + l16 + dj][c0 + 4 * quad];
            floatx4 z = bv;   // bias pre-ReLU as accumulator init
            z = __builtin_amdgcn_mfma_f32_16x16x32_bf16(a0, bfrag[nt][0], z, 0, 0, 0);
            z = __builtin_amdgcn_mfma_f32_16x16x32_bf16(a1, bfrag[nt][1], z, 0, 0, 0);
#pragma unroll
            for (int rg = 0; rg < 4; ++rg)
                acc[nt][rg] = fmaf(fmaxf(z[rg], 0.f), bf2f(ph[rg]), acc[nt][rg]);
        }
    }

    // ---- epilogue: stores directly from MFMA-layout acc ----
    float* ob = out + (size_t)b * CC * HW + h * WW + w0;
#pragma unroll
    for (int nt = 0; nt < 4; ++nt)
#pragma unroll
        for (int rg = 0; rg < 4; ++rg)
            ob[(c0 + 4 * quad + rg) * HW + nt * 16 + l16] = acc[nt][rg];
}

extern "C" void kernel_launch(void* const* d_in, const int* in_sizes, int n_in,
                              void* d_out, int out_size, void* d_ws, size_t ws_size,
                              hipStream_t stream) {
    const float* x  = (const float*)d_in[0];
    const float* Wg = (const float*)d_in[1];
    const float* bg = (const float*)d_in[2];
    float* out = (float*)d_out;
    unsigned short* Wb = (unsigned short*)d_ws;            // 73728 B
    float* Bp = (float*)((char*)d_ws + OO * CC * 2);       // + 2304 B

    ACDA_wconv_kernel<<<dim3((OO * CC + 255) / 256), dim3(256), 0, stream>>>(Wg, bg, Wb, Bp);
    ACDA_main_kernel<<<dim3(8 * 128 * 2), dim3(256), 0, stream>>>(x, Wb, Bp, out);
}